// Round 1
// baseline (1921.147 us; speedup 1.0000x reference)
//
#include <hip/hip_runtime.h>
#include <math.h>

// ---------------------------------------------------------------------------
// Net_75505525064500: 2-level SplineConv (K=3^3=27 kernels, degree-1 B-spline,
// mean aggregation, root weight + bias) + cluster max-pool + graph mean + MLP.
// Sizes (static for this problem, derived from in_sizes at launch):
//   N=80000 (Cin=2), E=1280000, N1=40000 (C=8), N2=20000 (C=16), B=16.
// Strategy: fused edge kernels, W in LDS (padded strides for bank spread),
// hardware f32 atomics for segment sums, monotone-uint atomicMax for seg_max.
// ---------------------------------------------------------------------------

__device__ __forceinline__ float eluf(float x) {
    return x > 0.f ? x : (expf(x) - 1.f);
}

// Monotone order-preserving encode of float into uint for atomicMax.
// encode(-inf)=0x007FFFFF; init value 0 is below every finite encode -> marks empty.
__device__ __forceinline__ unsigned encf(float f) {
    unsigned u = __float_as_uint(f);
    return (u & 0x80000000u) ? ~u : (u | 0x80000000u);
}
__device__ __forceinline__ float dec_or_zero(unsigned u) {
    if (u <= 0x007FFFFFu) return 0.f;  // empty segment (or -inf) -> 0
    return (u & 0x80000000u) ? __uint_as_float(u & 0x7FFFFFFFu)
                             : __uint_as_float(~u);
}

struct Basis {
    float wx[2], wy[2], wz[2];
    int ibase;
};

// Open B-spline basis, degree 1, K=3 per dim: v = p*2, i0=clip(floor(v),0,1), f=v-i0.
__device__ __forceinline__ Basis mkbasis(float px, float py, float pz) {
    float vx = px * 2.f, vy = py * 2.f, vz = pz * 2.f;
    float ix = fmaxf(fminf(floorf(vx), 1.f), 0.f);
    float iy = fmaxf(fminf(floorf(vy), 1.f), 0.f);
    float iz = fmaxf(fminf(floorf(vz), 1.f), 0.f);
    float fx = vx - ix, fy = vy - iy, fz = vz - iz;
    Basis b;
    b.wx[0] = 1.f - fx; b.wx[1] = fx;
    b.wy[0] = 1.f - fy; b.wy[1] = fy;
    b.wz[0] = 1.f - fz; b.wz[1] = fz;
    b.ibase = (int)ix + 3 * (int)iy + 9 * (int)iz;
    return b;
}

#define W1_STRIDE 20   // 16 floats payload + pad; multiples of 4 keep float4 spans disjoint
#define W2_STRIDE 132  // 128 floats payload + pad

// ---- level 1 edge kernel: msg[e] = sum_s basis * (x[src] @ W1[kidx_s]) -> atomic agg ----
__global__ __launch_bounds__(256) void edge1_kernel(
    const int* __restrict__ ei, const float* __restrict__ attr,
    const float* __restrict__ x, const float* __restrict__ W1,
    float* __restrict__ agg1, float* __restrict__ cnt1, int E)
{
    __shared__ float lw[27 * W1_STRIDE];
    for (int i = threadIdx.x; i < 27 * 16; i += 256)
        lw[(i >> 4) * W1_STRIDE + (i & 15)] = W1[i];
    __syncthreads();

    int e = blockIdx.x * 256 + threadIdx.x;
    if (e >= E) return;

    int s = ei[e];
    int d = ei[E + e];
    Basis b = mkbasis(attr[3 * e], attr[3 * e + 1], attr[3 * e + 2]);
    float x0 = x[2 * s], x1v = x[2 * s + 1];

    float m[8];
#pragma unroll
    for (int o = 0; o < 8; ++o) m[o] = 0.f;

#pragma unroll
    for (int cz = 0; cz < 2; ++cz)
#pragma unroll
    for (int cy = 0; cy < 2; ++cy)
#pragma unroll
    for (int cx = 0; cx < 2; ++cx) {
        float w = b.wx[cx] * b.wy[cy] * b.wz[cz];
        int k = b.ibase + cx + 3 * cy + 9 * cz;
        const float* Wk = &lw[k * W1_STRIDE];
        float a = w * x0, bb = w * x1v;
        const float4 wa0 = *(const float4*)&Wk[0];
        const float4 wa1 = *(const float4*)&Wk[4];
        const float4 wb0 = *(const float4*)&Wk[8];
        const float4 wb1 = *(const float4*)&Wk[12];
        m[0] += a * wa0.x + bb * wb0.x;
        m[1] += a * wa0.y + bb * wb0.y;
        m[2] += a * wa0.z + bb * wb0.z;
        m[3] += a * wa0.w + bb * wb0.w;
        m[4] += a * wa1.x + bb * wb1.x;
        m[5] += a * wa1.y + bb * wb1.y;
        m[6] += a * wa1.z + bb * wb1.z;
        m[7] += a * wa1.w + bb * wb1.w;
    }

    float* ad = &agg1[(size_t)d * 8];
#pragma unroll
    for (int o = 0; o < 8; ++o) unsafeAtomicAdd(&ad[o], m[o]);
    unsafeAtomicAdd(&cnt1[d], 1.f);
}

// ---- level 1 node: h = elu(agg/cnt + x@root1 + b1); scatter-max into clusters ----
__global__ __launch_bounds__(256) void node1_kernel(
    const float* __restrict__ x, const float* __restrict__ agg1,
    const float* __restrict__ cnt1,
    const float* __restrict__ root1, const float* __restrict__ b1,
    const int* __restrict__ cluster1, const int* __restrict__ batch,
    unsigned* __restrict__ enc1, int* __restrict__ batch1, int N)
{
    int n = blockIdx.x * 256 + threadIdx.x;
    if (n >= N) return;
    float inv = 1.f / fmaxf(cnt1[n], 1.f);
    float x0 = x[2 * n], x1v = x[2 * n + 1];
    int c = cluster1[n];
    unsigned* ec = &enc1[(size_t)c * 8];
#pragma unroll
    for (int o = 0; o < 8; ++o) {
        float h = eluf(agg1[(size_t)n * 8 + o] * inv +
                       x0 * root1[o] + x1v * root1[8 + o] + b1[o]);
        atomicMax(&ec[o], encf(h));
    }
    atomicMax(&batch1[c], batch[n]);  // init 0; batch >= 0 -> matches maximum(segmax,0)
}

__global__ __launch_bounds__(256) void decode_kernel(
    const unsigned* __restrict__ enc, float* __restrict__ out, int n)
{
    int i = blockIdx.x * 256 + threadIdx.x;
    if (i < n) out[i] = dec_or_zero(enc[i]);
}

// ---- level 2 edge kernel: 8 corners x (8x16) W2 blend from LDS ----
__global__ __launch_bounds__(256) void edge2_kernel(
    const int* __restrict__ ei, const float* __restrict__ attr,
    const int* __restrict__ cluster1, const float* __restrict__ x1,
    const float* __restrict__ W2,
    float* __restrict__ agg2, float* __restrict__ cnt2, int E)
{
    __shared__ float lw[27 * W2_STRIDE];
    for (int i = threadIdx.x; i < 27 * 128; i += 256)
        lw[(i >> 7) * W2_STRIDE + (i & 127)] = W2[i];
    __syncthreads();

    int e = blockIdx.x * 256 + threadIdx.x;
    if (e >= E) return;

    int s2 = cluster1[ei[e]];
    int d2 = cluster1[ei[E + e]];
    Basis b = mkbasis(attr[3 * e], attr[3 * e + 1], attr[3 * e + 2]);

    const float4* xr4 = (const float4*)&x1[(size_t)s2 * 8];
    float4 xa = xr4[0], xb = xr4[1];
    float xr[8] = {xa.x, xa.y, xa.z, xa.w, xb.x, xb.y, xb.z, xb.w};

    float acc[16];
#pragma unroll
    for (int o = 0; o < 16; ++o) acc[o] = 0.f;

#pragma unroll
    for (int cz = 0; cz < 2; ++cz)
#pragma unroll
    for (int cy = 0; cy < 2; ++cy)
#pragma unroll
    for (int cx = 0; cx < 2; ++cx) {
        float w = b.wx[cx] * b.wy[cy] * b.wz[cz];
        int k = b.ibase + cx + 3 * cy + 9 * cz;
        const float* Wk = &lw[k * W2_STRIDE];
#pragma unroll
        for (int c = 0; c < 8; ++c) {
            float a = w * xr[c];
            const float4 w0 = *(const float4*)&Wk[c * 16 + 0];
            const float4 w1 = *(const float4*)&Wk[c * 16 + 4];
            const float4 w2 = *(const float4*)&Wk[c * 16 + 8];
            const float4 w3 = *(const float4*)&Wk[c * 16 + 12];
            acc[0]  += a * w0.x; acc[1]  += a * w0.y; acc[2]  += a * w0.z; acc[3]  += a * w0.w;
            acc[4]  += a * w1.x; acc[5]  += a * w1.y; acc[6]  += a * w1.z; acc[7]  += a * w1.w;
            acc[8]  += a * w2.x; acc[9]  += a * w2.y; acc[10] += a * w2.z; acc[11] += a * w2.w;
            acc[12] += a * w3.x; acc[13] += a * w3.y; acc[14] += a * w3.z; acc[15] += a * w3.w;
        }
    }

    float* ad = &agg2[(size_t)d2 * 16];
#pragma unroll
    for (int o = 0; o < 16; ++o) unsafeAtomicAdd(&ad[o], acc[o]);
    unsafeAtomicAdd(&cnt2[d2], 1.f);
}

// ---- level 2 node: h2 = elu(agg2/cnt2 + x1@root2 + b2); scatter-max into cluster2 ----
__global__ __launch_bounds__(256) void node2_kernel(
    const float* __restrict__ x1, const float* __restrict__ agg2,
    const float* __restrict__ cnt2,
    const float* __restrict__ root2, const float* __restrict__ b2,
    const int* __restrict__ cluster2, const int* __restrict__ batch1,
    unsigned* __restrict__ enc2, int* __restrict__ batch2, int N1)
{
    int n = blockIdx.x * 256 + threadIdx.x;
    if (n >= N1) return;
    float inv = 1.f / fmaxf(cnt2[n], 1.f);
    float xr[8];
#pragma unroll
    for (int c = 0; c < 8; ++c) xr[c] = x1[(size_t)n * 8 + c];
    int c2 = cluster2[n];
    unsigned* ec = &enc2[(size_t)c2 * 16];
#pragma unroll
    for (int o = 0; o < 16; ++o) {
        float v = agg2[(size_t)n * 16 + o] * inv + b2[o];
#pragma unroll
        for (int c = 0; c < 8; ++c) v += xr[c] * root2[c * 16 + o];
        atomicMax(&ec[o], encf(eluf(v)));
    }
    atomicMax(&batch2[c2], batch1[n]);
}

// ---- per-graph mean: block-level LDS reduction then few global atomics ----
__global__ __launch_bounds__(256) void batchred_kernel(
    const unsigned* __restrict__ enc2, const int* __restrict__ batch2,
    float* __restrict__ gsum, float* __restrict__ gcnt, int N2)
{
    __shared__ float ls[16 * 16];
    __shared__ float lc[16];
    for (int i = threadIdx.x; i < 256; i += 256) ls[i] = 0.f;
    if (threadIdx.x < 16) lc[threadIdx.x] = 0.f;
    __syncthreads();

    int n = blockIdx.x * 256 + threadIdx.x;
    if (n < N2) {
        int bg = batch2[n];  // init 0, values >= 0 -> matches maximum(segmax,0)
#pragma unroll
        for (int o = 0; o < 16; ++o) {
            float v = dec_or_zero(enc2[(size_t)n * 16 + o]);
            atomicAdd(&ls[bg * 16 + o], v);
        }
        atomicAdd(&lc[bg], 1.f);
    }
    __syncthreads();
    for (int i = threadIdx.x; i < 256; i += 256) unsafeAtomicAdd(&gsum[i], ls[i]);
    if (threadIdx.x < 16) unsafeAtomicAdd(&gcnt[threadIdx.x], lc[threadIdx.x]);
}

// ---- head: g = gsum/max(gcnt,1); elu(g@fc1+b); elu(h@fc2+b) -> out[B] ----
__global__ __launch_bounds__(256) void head_kernel(
    const float* __restrict__ gsum, const float* __restrict__ gcnt,
    const float* __restrict__ fc1_w, const float* __restrict__ fc1_b,
    const float* __restrict__ fc2_w, const float* __restrict__ fc2_b,
    float* __restrict__ out, int B)
{
    __shared__ float g[16 * 16];
    __shared__ float h1[16 * 64];
    int t = threadIdx.x;
    if (t < B * 16) {
        int b = t >> 4;
        g[t] = gsum[t] / fmaxf(gcnt[b], 1.f);
    }
    __syncthreads();
    for (int j = t; j < B * 64; j += 256) {
        int b = j >> 6, jj = j & 63;
        float s = fc1_b[jj];
#pragma unroll
        for (int c = 0; c < 16; ++c) s += g[b * 16 + c] * fc1_w[c * 64 + jj];
        h1[j] = eluf(s);
    }
    __syncthreads();
    if (t < B) {
        float s = fc2_b[0];
#pragma unroll
        for (int j = 0; j < 64; ++j) s += h1[t * 64 + j] * fc2_w[j];
        out[t] = eluf(s);
    }
}

extern "C" void kernel_launch(void* const* d_in, const int* in_sizes, int n_in,
                              void* d_out, int out_size, void* d_ws, size_t ws_size,
                              hipStream_t stream)
{
    const float* x        = (const float*)d_in[0];
    const int*   ei       = (const int*)  d_in[1];
    const float* attr     = (const float*)d_in[2];
    const int*   batch    = (const int*)  d_in[3];
    const int*   cluster1 = (const int*)  d_in[4];
    const int*   cluster2 = (const int*)  d_in[5];
    const float* W1       = (const float*)d_in[6];
    const float* root1    = (const float*)d_in[7];
    const float* b1       = (const float*)d_in[8];
    const float* W2       = (const float*)d_in[9];
    const float* root2    = (const float*)d_in[10];
    const float* b2       = (const float*)d_in[11];
    const float* fc1_w    = (const float*)d_in[12];
    const float* fc1_b    = (const float*)d_in[13];
    const float* fc2_w    = (const float*)d_in[14];
    const float* fc2_b    = (const float*)d_in[15];

    const int N  = in_sizes[0] / 2;
    const int E  = in_sizes[1] / 2;
    const int N1 = in_sizes[5];
    const int N2 = N1 / 2;
    const int B  = out_size;

    float* ws = (float*)d_ws;
    size_t off = 0;
    float*    agg1   = ws + off;               off += (size_t)N  * 8;
    float*    cnt1   = ws + off;               off += (size_t)N;
    unsigned* enc1   = (unsigned*)(ws + off);  off += (size_t)N1 * 8;
    int*      batch1 = (int*)(ws + off);       off += (size_t)N1;
    float*    x1     = ws + off;               off += (size_t)N1 * 8;
    float*    agg2   = ws + off;               off += (size_t)N1 * 16;
    float*    cnt2   = ws + off;               off += (size_t)N1;
    unsigned* enc2   = (unsigned*)(ws + off);  off += (size_t)N2 * 16;
    int*      batch2 = (int*)(ws + off);       off += (size_t)N2;
    float*    gsum   = ws + off;               off += (size_t)B * 16;
    float*    gcnt   = ws + off;               off += (size_t)B;

    // zero all accumulators (also serves as -inf marker for the max-encodings)
    hipMemsetAsync(d_ws, 0, off * sizeof(float), stream);

    const int eb = (E + 255) / 256;
    edge1_kernel<<<eb, 256, 0, stream>>>(ei, attr, x, W1, agg1, cnt1, E);
    node1_kernel<<<(N + 255) / 256, 256, 0, stream>>>(
        x, agg1, cnt1, root1, b1, cluster1, batch, enc1, batch1, N);
    decode_kernel<<<(N1 * 8 + 255) / 256, 256, 0, stream>>>(enc1, x1, N1 * 8);
    edge2_kernel<<<eb, 256, 0, stream>>>(ei, attr, cluster1, x1, W2, agg2, cnt2, E);
    node2_kernel<<<(N1 + 255) / 256, 256, 0, stream>>>(
        x1, agg2, cnt2, root2, b2, cluster2, batch1, enc2, batch2, N1);
    batchred_kernel<<<(N2 + 255) / 256, 256, 0, stream>>>(enc2, batch2, gsum, gcnt, N2);
    head_kernel<<<1, 256, 0, stream>>>(gsum, gcnt, fc1_w, fc1_b, fc2_w, fc2_b,
                                       (float*)d_out, B);
}